// Round 1
// baseline (212.641 us; speedup 1.0000x reference)
//
#include <hip/hip_runtime.h>

// Problem constants (from reference setup_inputs)
#define BB   64          // batch
#define SS   512         // seq len
#define HH   768         // hidden dim
#define WW   256         // MAX_WORD_LEN (words per batch)
#define WE   300         // word-embedding dim
#define OUTD (HH + WE)   // 1068 output feature dim

#define WPB  4           // words per block
#define GPB  (WW / WPB)  // word-groups per batch row = 64

// One block per (b, group-of-4-words). token_ids are sorted per row, so the
// 4 words own contiguous token runs; the block computes their boundaries
// WITHOUT binary search: stage the 2KB token row in LDS (parallel load),
// then each thread scatters the segment-start positions for transitions
// tk[s-1]->tk[s] that land in the block's window [w0, w0+WPB]. This removes
// the 18-deep dependent-load chain the previous version paid per block.
//
// Waves 0-2 (192 threads): each thread owns one float4 column of the 768-dim
// mean, looping over the 4 words (avg ~8 independent global loads/thread).
// Wave 3 (64 threads): copies the 4 w2v rows (4 x 75 float4).
// All global accesses are float4-aligned (HH=768, WE=300, OUTD=1068 -> all
// row strides are multiples of 16B).
__global__ __launch_bounds__(256)
void EmbeddingsModule_45311904973549_kernel(
    const float* __restrict__ hidden,     // [B, S, H]
    const float* __restrict__ w2v,        // [VOCAB, WE]
    const int*   __restrict__ token_ids,  // [B, S] sorted per row, in [0,W)
    const int*   __restrict__ word_ids,   // [B, W] in [0,VOCAB)
    float*       __restrict__ out)        // [B, W, OUTD]
{
    __shared__ int tk[SS];
    __shared__ int LB[WPB + 1];   // LB[k] = first s with tk[s] >= w0+k

    const int blk = blockIdx.x;           // 0 .. BB*GPB-1
    const int b   = blk / GPB;
    const int w0  = (blk % GPB) * WPB;
    const int tid = threadIdx.x;

    // ---- Phase 1: stage token row (512 ints, int2 per thread) + init bounds
    ((int2*)tk)[tid] = ((const int2*)(token_ids + (size_t)b * SS))[tid];
    if (tid <= WPB) LB[tid] = SS;         // default: word starts past the end
    __syncthreads();

    // ---- Phase 2: scatter segment starts for this block's 5 boundaries.
    // For each position s with t=tk[s], tp=tk[s-1] (tp=-1 at s=0), every word
    // w in (tp, t] has lower_bound = s. Each LB[k] is written by at most one
    // thread (the unique transition position), so no race.
    #pragma unroll
    for (int u = 0; u < 2; ++u) {
        const int s  = tid * 2 + u;
        const int t  = tk[s];
        const int tp = (s == 0) ? -1 : tk[s - 1];
        int klo = tp + 1 - w0; if (klo < 0)   klo = 0;
        int khi = t - w0;      if (khi > WPB) khi = WPB;
        for (int k = klo; k <= khi; ++k) LB[k] = s;
    }
    __syncthreads();

    if (tid < 192) {
        // ---- segment means: thread owns float4 column `tid` for 4 words
        const float4* hrow = (const float4*)(hidden + (size_t)b * SS * HH);
        #pragma unroll
        for (int k = 0; k < WPB; ++k) {
            const int lo = LB[k], hi = LB[k + 1];
            float4 acc = make_float4(0.f, 0.f, 0.f, 0.f);
            for (int s = lo; s < hi; ++s) {
                float4 v = hrow[(size_t)s * (HH / 4) + tid];
                acc.x += v.x; acc.y += v.y; acc.z += v.z; acc.w += v.w;
            }
            const float inv = (hi > lo) ? (1.0f / (float)(hi - lo)) : 0.0f;
            acc.x *= inv; acc.y *= inv; acc.z *= inv; acc.w *= inv;
            float4* orow = (float4*)(out + (size_t)(b * WW + w0 + k) * OUTD);
            orow[tid] = acc;              // out[b, w0+k, 0:768]
        }
    } else {
        // ---- w2v gather: 4 rows x 75 float4 with 64 threads
        const int t64 = tid - 192;
        int wid[WPB];
        #pragma unroll
        for (int k = 0; k < WPB; ++k) wid[k] = word_ids[b * WW + w0 + k];
        #pragma unroll
        for (int k = 0; k < WPB; ++k) {
            const float4* wrow  = (const float4*)(w2v + (size_t)wid[k] * WE);
            float4*       obase = (float4*)(out + (size_t)(b * WW + w0 + k) * OUTD + HH);
            for (int j = t64; j < WE / 4; j += 64) {
                obase[j] = wrow[j];       // out[b, w0+k, 768:1068]
            }
        }
    }
}

extern "C" void kernel_launch(void* const* d_in, const int* in_sizes, int n_in,
                              void* d_out, int out_size, void* d_ws, size_t ws_size,
                              hipStream_t stream) {
    const float* hidden    = (const float*)d_in[0];
    const float* w2v       = (const float*)d_in[1];
    const int*   token_ids = (const int*)d_in[2];
    const int*   word_ids  = (const int*)d_in[3];
    float*       out       = (float*)d_out;

    EmbeddingsModule_45311904973549_kernel<<<BB * GPB, 256, 0, stream>>>(
        hidden, w2v, token_ids, word_ids, out);
}